// Round 21
// baseline (137.552 us; speedup 1.0000x reference)
//
#include <hip/hip_runtime.h>
#include <stdint.h>

#define BB  32
#define CC  256
#define SS  1024
#define GG  32
#define GCH 8
#define EPS 1e-5f

typedef __attribute__((ext_vector_type(8))) short short8;
typedef __attribute__((ext_vector_type(4))) float f32x4;
typedef __attribute__((ext_vector_type(16))) float f32x16;
typedef unsigned short ushort;

__device__ __forceinline__ float bf2f(ushort u){
  union { unsigned int i; float f; } v; v.i = ((unsigned int)u) << 16; return v.f;
}
__device__ __forceinline__ ushort f2bf(float f){
  union { float f; unsigned int i; } v; v.f = f;
  unsigned int r = v.i + 0x7FFFu + ((v.i >> 16) & 1u);
  return (ushort)(r >> 16);
}
__device__ __forceinline__ unsigned int cvt_pk_bf16(float lo, float hi){
  unsigned int r;
  asm("v_cvt_pk_bf16_f32 %0, %1, %2" : "=v"(r) : "v"(lo), "v"(hi));
  return r;
}

// per-block dtype sniff: wave-uniform, same answer in every wave/block.
__device__ __forceinline__ int sniff_inline(const void* xp){
  const unsigned int* xw = (const unsigned int*)xp;
  const int lane = threadIdx.x & 63;
  int ok = 0;
  #pragma unroll
  for (int j = 0; j < 4; j++){
    unsigned int w = xw[lane*4 + j];
    ushort lo = (ushort)(w & 0xFFFFu);
    int e = (lo >> 7) & 0xFF;
    ok += (lo == 0 || (e >= 100 && e <= 130)) ? 1 : 0;
  }
  #pragma unroll
  for (int o = 32; o > 0; o >>= 1) ok += __shfl_down(ok, o);
  ok = __shfl(ok, 0);
  return ok > 192;
}

typedef __attribute__((address_space(3))) unsigned int lds_uint;
typedef const __attribute__((address_space(1))) unsigned int glob_uint;
__device__ __forceinline__ void ld_lds16(const void* g, void* l){
  __builtin_amdgcn_global_load_lds((glob_uint*)g, (lds_uint*)l, 16, 0, 0);
}

// ---------- fused pre-pass: blocks 0..63 convert weights/biases; 64..1087 GN stats ----------
// WT[z][n][k] = W[z][k][n] bf16; z==0 scaled by 1/16*log2(e) (exp2-domain softmax).
__global__ __launch_bounds__(256) void pre_kernel(
    const void* x,
    const void* w0, const void* w1, const void* w2, const void* w3,
    const void* b0, const void* b1, const void* b2, const void* b3,
    ushort* __restrict__ WT, float* __restrict__ biasF,
    float* __restrict__ stats)
{
  const int f = sniff_inline(x);
  const int tid = threadIdx.x;
  if (blockIdx.x < 64){
    const int id = blockIdx.x;
    const int z = id >> 4, yb = (id >> 2) & 3, xb = id & 3;
    const float scl = (z == 0) ? 0.0901684400557f : 1.0f;   // 0.0625 * log2(e)
    const void* wsel = z==0?w0:z==1?w1:z==2?w2:w3;
    ushort* dst = WT + (long long)z * 65536;
    __shared__ ushort t[64][65];
    const int tx = tid & 63, ty = tid >> 6;
    const int r0 = xb * 64, c0 = yb * 64;
    for (int j = 0; j < 64; j += 4){
      const int idx = (r0+ty+j)*256 + c0+tx;
      float v = f ? bf2f(((const ushort*)wsel)[idx]) : ((const float*)wsel)[idx];
      t[ty+j][tx] = f2bf(v * scl);
    }
    __syncthreads();
    for (int j = 0; j < 64; j += 4) dst[(c0+ty+j)*256 + r0+tx] = t[tx][ty+j];
    if (xb == 0 && yb == 0){
      const void* bsel = z==0?b0:z==1?b1:z==2?b2:b3;
      float bv = f ? bf2f(((const ushort*)bsel)[tid]) : ((const float*)bsel)[tid];
      biasF[z*256 + tid] = bv * scl;
    }
  } else {
    const int id = blockIdx.x - 64;
    const int g = id & 31, b = id >> 5;
    const long long base = ((long long)b * CC + g * GCH) * SS;
    float sum = 0.f, ss = 0.f;
    if (f){
      const ushort* xg = (const ushort*)x + base;
      #pragma unroll
      for (int j = 0; j < 4; j++){
        uint4 u = *(const uint4*)(xg + (j*256 + tid)*8);
        const ushort* e = (const ushort*)&u;
        #pragma unroll
        for (int i = 0; i < 8; i++){ float v = bf2f(e[i]); sum += v; ss += v*v; }
      }
    } else {
      const float* xg = (const float*)x + base;
      #pragma unroll
      for (int j = 0; j < 8; j++){
        float4 v4 = *(const float4*)(xg + (j*256 + tid)*4);
        sum += v4.x+v4.y+v4.z+v4.w;
        ss  += v4.x*v4.x+v4.y*v4.y+v4.z*v4.z+v4.w*v4.w;
      }
    }
    __shared__ float red[8];
    const int lane = tid & 63, w = tid >> 6;
    #pragma unroll
    for (int o = 32; o > 0; o >>= 1){
      sum += __shfl_down(sum, o);
      ss  += __shfl_down(ss, o);
    }
    if (lane == 0){ red[w] = sum; red[4+w] = ss; }
    __syncthreads();
    if (tid == 0){
      float s1 = red[0]+red[1]+red[2]+red[3];
      float s2 = red[4]+red[5]+red[6]+red[7];
      float mean = s1 / (float)(GCH*SS);
      float var  = s2 / (float)(GCH*SS) - mean*mean;
      const int idx = b*GG + g;
      stats[idx*2]   = mean;
      stats[idx*2+1] = rsqrtf(var + EPS);
    }
  }
}

// ---------- GN pass 2 ----------
__global__ __launch_bounds__(256) void gn_norm(const void* __restrict__ x,
                                               ushort* __restrict__ h,
                                               const float* __restrict__ stats)
{
  const int f = sniff_inline(x);
  const int c0 = blockIdx.x * 64, s0 = blockIdx.y * 64, b = blockIdx.z;
  const int tid = threadIdx.x;
  __shared__ ushort T[64][72];
  const int row = tid >> 2;
  const int qr  = tid & 3;
  const int g = (c0 + row) >> 3;
  const float mean = stats[(b*GG + g)*2];
  const float rstd = stats[(b*GG + g)*2 + 1];
  const long long xrow = ((long long)b * CC + c0 + row) * SS + s0;
  if (f){
    const ushort* xr = (const ushort*)x + xrow;
    #pragma unroll
    for (int j = 0; j < 2; j++){
      const int col = qr*16 + j*8;
      uint4 u = *(const uint4*)(xr + col);
      const ushort* e = (const ushort*)&u;
      #pragma unroll
      for (int i = 0; i < 8; i++) T[row][col+i] = f2bf((bf2f(e[i]) - mean) * rstd);
    }
  } else {
    const float* xr = (const float*)x + xrow;
    #pragma unroll
    for (int j = 0; j < 4; j++){
      const int col = qr*16 + j*4;
      float4 v4 = *(const float4*)(xr + col);
      T[row][col+0] = f2bf((v4.x - mean) * rstd);
      T[row][col+1] = f2bf((v4.y - mean) * rstd);
      T[row][col+2] = f2bf((v4.z - mean) * rstd);
      T[row][col+3] = f2bf((v4.w - mean) * rstd);
    }
  }
  __syncthreads();
  #pragma unroll
  for (int pass = 0; pass < 2; pass++){
    const int sr = pass*32 + (tid >> 3);
    const int cl = (tid & 7) * 8;
    ushort tmp[8];
    #pragma unroll
    for (int e = 0; e < 8; e++) tmp[e] = T[cl+e][sr];
    *(uint4*)(&h[((long long)b * SS + s0 + sr) * CC + c0 + cl]) = *(const uint4*)tmp;
  }
}

// ---------- generic 128x128 MFMA GEMM, m97-class staging ----------
template<int MODE>
__global__ __launch_bounds__(256) void gemm128(
    const ushort* __restrict__ A,
    const ushort* __restrict__ BT,
    ushort* __restrict__ Cmat,
    int lda, int ldb, int ldc, int K,
    long long sA, long long sB, long long sC,
    const float* __restrict__ biasF,
    const void* __restrict__ xres,
    void* __restrict__ outp,
    ushort* __restrict__ vTp,
    long long xoff)
{
  extern __shared__ __attribute__((aligned(16))) ushort smem[];
  ushort* As = smem;
  ushort* Bs = smem + 8192;
  const int tid  = threadIdx.x;
  const int lane = tid & 63;
  const int w    = tid >> 6;
  const int wr   = w >> 1, wc = w & 1;
  const int bz   = blockIdx.z;
  const int m0 = blockIdx.x * 128;
  const int n0 = blockIdx.y * 128;

  const int rr = lane & 15;
  const int hi = lane >> 4;
  const int crow = lane >> 3;
  const int pslot = lane & 7;

  f32x4 acc[4][4] = {};

  const ushort* Ab = A + (long long)bz * sA;
  const ushort* Bb = BT + (long long)bz * sB;

  for (int k0 = 0; k0 < K; k0 += 64){
    #pragma unroll
    for (int j = 0; j < 4; j++){
      const int ck = w*4 + j;
      const int r  = ck*8 + crow;
      const int s  = pslot ^ (r & 7);
      ld_lds16(Ab + (long long)(m0 + r) * lda + k0 + s*8, &As[ck * 512]);
    }
    #pragma unroll
    for (int j = 0; j < 4; j++){
      const int ck = w*4 + j;
      const int r  = ck*8 + crow;
      const int s  = pslot ^ (r & 7);
      ld_lds16(Bb + (long long)(n0 + r) * ldb + k0 + s*8, &Bs[ck * 512]);
    }
    asm volatile("s_waitcnt vmcnt(0)" ::: "memory");
    __builtin_amdgcn_sched_barrier(0);
    __syncthreads();

    #pragma unroll
    for (int kk = 0; kk < 2; kk++){
      short8 af[4], bfr[4];
      const int lbyte = kk*64 + hi*16;
      #pragma unroll
      for (int mf = 0; mf < 4; mf++){
        const int row = wr*64 + mf*16 + rr;
        af[mf] = *(const short8*)((const char*)As + row*128 + (lbyte ^ ((row & 7) << 4)));
      }
      #pragma unroll
      for (int nf = 0; nf < 4; nf++){
        const int row = wc*64 + nf*16 + rr;
        bfr[nf] = *(const short8*)((const char*)Bs + row*128 + (lbyte ^ ((row & 7) << 4)));
      }
      #pragma unroll
      for (int mf = 0; mf < 4; mf++)
        #pragma unroll
        for (int nf = 0; nf < 4; nf++)
          acc[mf][nf] = __builtin_amdgcn_mfma_f32_16x16x32_bf16(af[mf], bfr[nf], acc[mf][nf], 0, 0, 0);
    }
    __syncthreads();
  }

  const int rb = 4 * (lane >> 4);
  if (MODE == 0){
    if (bz < 2){
      ushort* Co = Cmat + (long long)bz * sC;
      #pragma unroll
      for (int mf = 0; mf < 4; mf++){
        #pragma unroll
        for (int nf = 0; nf < 4; nf++){
          const int col = n0 + wc*64 + nf*16 + rr;
          const float badd = biasF[bz*256 + col];
          #pragma unroll
          for (int r = 0; r < 4; r++){
            const int row = m0 + wr*64 + mf*16 + rb + r;
            Co[(long long)row * ldc + col] = f2bf(acc[mf][nf][r] + badd);
          }
        }
      }
    } else {
      // v: LDS-transpose then vectorized store to vT[b][c][s]
      #pragma unroll
      for (int mf = 0; mf < 4; mf++){
        #pragma unroll
        for (int nf = 0; nf < 4; nf++){
          const int colL = wc*64 + nf*16 + rr;
          const float badd = biasF[512 + n0 + colL];
          #pragma unroll
          for (int r = 0; r < 4; r++){
            const int rowL = wr*64 + mf*16 + rb + r;
            smem[colL * 128 + rowL] = f2bf(acc[mf][nf][r] + badd);
          }
        }
      }
      __syncthreads();
      const int bL = m0 >> 10;
      const int s0 = m0 & 1023;
      for (int i = tid; i < 2048; i += 256){
        const int colL = i >> 4;
        const int rowL = (i & 15) * 8;
        uint4 pv = *(const uint4*)(&smem[colL * 128 + rowL]);
        *(uint4*)(&vTp[((long long)bL * CC + n0 + colL) * SS + s0 + rowL]) = pv;
      }
    }
  } else {
    const int bL = m0 >> 10;
    const int s0 = m0 & 1023;
    #pragma unroll
    for (int mf = 0; mf < 4; mf++){
      #pragma unroll
      for (int nf = 0; nf < 4; nf++){
        const int colL = wc*64 + nf*16 + rr;
        const float badd = biasF[768 + n0 + colL];
        #pragma unroll
        for (int r = 0; r < 4; r++){
          const int rowL = wr*64 + mf*16 + rb + r;
          smem[colL * 128 + rowL] = f2bf(acc[mf][nf][r] + badd);
        }
      }
    }
    __syncthreads();
    const int f = sniff_inline(xres);
    for (int i = tid; i < 2048; i += 256){
      const int colL = i >> 4;
      const int rowL = (i & 15) * 8;
      const long long oi = xoff + ((long long)bL * CC + n0 + colL) * SS + s0 + rowL;
      const ushort* pu = &smem[colL * 128 + rowL];
      if (f){
        const ushort* xu = (const ushort*)xres + oi;
        ushort* ou = (ushort*)outp + oi;
        ushort tmp[8];
        #pragma unroll
        for (int e = 0; e < 8; e++) tmp[e] = f2bf(bf2f(xu[e]) + bf2f(pu[e]));
        *(uint4*)ou = *(const uint4*)tmp;
      } else {
        const float* xf = (const float*)xres + oi;
        float* of = (float*)outp + oi;
        float4 a0 = *(const float4*)xf;
        float4 a1 = *(const float4*)(xf + 4);
        float4 r0, r1;
        r0.x = a0.x + bf2f(pu[0]); r0.y = a0.y + bf2f(pu[1]);
        r0.z = a0.z + bf2f(pu[2]); r0.w = a0.w + bf2f(pu[3]);
        r1.x = a1.x + bf2f(pu[4]); r1.y = a1.y + bf2f(pu[5]);
        r1.z = a1.z + bf2f(pu[6]); r1.w = a1.w + bf2f(pu[7]);
        *(float4*)of = r0;
        *(float4*)(of + 4) = r1;
      }
    }
  }
}

// ---------- fused flash attention v12: v10 compute, single-buffered K/V,
//            2 blocks/CU (cross-block overlap hides staging; r7 mechanism) ----------
__global__ __launch_bounds__(512, 1) void attn_fused(
    const ushort* __restrict__ q, const ushort* __restrict__ k,
    const ushort* __restrict__ vT, ushort* __restrict__ oC)
{
  __shared__ ushort Kb[64 * 256];   // 32KB; reused as merge O buf (qg 0,1)
  __shared__ ushort Vb[256 * 64];   // 32KB; reused as merge O buf (qg 2,3)
  __shared__ float  Mb[8][32];
  __shared__ float  Lb[8][32];
  const int tid = threadIdx.x, lane = tid & 63, w = tid >> 6;
  const int l31 = lane & 31, hi2 = lane >> 5;
  const int qg = w & 3, ch = w >> 2;
  const int b = blockIdx.x, qt = blockIdx.y;

  const char* kgB = (const char*)(k + (long long)b * SS * CC);
  const char* vgB = (const char*)(vT + (long long)b * CC * SS);
  const int qrow = qt*128 + qg*32 + l31;
  const ushort* qgp = q + ((long long)b * SS + qrow) * CC + hi2*8;
  ushort* ogq = oC + ((long long)b * SS + qrow) * CC;

  short8 qf[16];
  #pragma unroll
  for (int kk = 0; kk < 16; kk++)
    qf[kk] = *(const short8*)(qgp + kk*16);

  f32x16 Oa[8] = {};
  float mrow = -1e30f, lrow = 0.0f;

  #define STAGE(t0)                                                             \
  {                                                                             \
    _Pragma("unroll")                                                           \
    for (int j = 0; j < 4; j++){                                                \
      const int ck = j*8 + w;                                                   \
      const int tr = ck*2 + (lane >> 5);                                        \
      const int xb = ((lane & 31) * 16) ^ ((tr & 31) << 4);                     \
      ld_lds16(kgB + (long long)((t0) + tr) * 512 + xb, &Kb[ck * 512]);         \
    }                                                                           \
    _Pragma("unroll")                                                           \
    for (int j = 0; j < 4; j++){                                                \
      const int ck = j*8 + w;                                                   \
      const int vr = ck*2 + (lane >> 5);                                        \
      const int u  = (lane & 31) ^ ((vr & 7) << 2);                             \
      const int vc = vr*4 + (u & 3);                                            \
      const int tb = (u >> 2) * 16;                                             \
      ld_lds16(vgB + (long long)vc * 2048 + (t0)*2 + tb, &Vb[ck * 512]);        \
    }                                                                           \
  }

  const int coff = hi2 * 16;
  const int kswz = l31 << 4;
  const int krow = ch*32 + l31;   // this wave's K row within the tile

  for (int t = 0; t < 16; t++){
    // previous iteration ended with a barrier -> buffers free to overwrite
    STAGE(t*64);
    asm volatile("s_waitcnt vmcnt(0)" ::: "memory");
    __builtin_amdgcn_sched_barrier(0);
    __syncthreads();

    // ---- S = mfma(K_half, Q): 16 MFMA; lane = q col l31, regs = kv rows ----
    f32x16 Sa = {};
    #pragma unroll
    for (int kk = 0; kk < 16; kk++){
      const int off = kk*32 + coff;
      short8 ka = *(const short8*)((const char*)Kb + krow*512 + (off ^ kswz));
      Sa = __builtin_amdgcn_mfma_f32_32x32x16_bf16(ka, qf[kk], Sa, 0, 0, 0);
    }

    // ---- in-register online softmax over this wave's 32-kv half ----
    float mx = Sa[0];
    #pragma unroll
    for (int r = 1; r < 16; r++) mx = fmaxf(mx, Sa[r]);
    mx = fmaxf(mx, __shfl_xor(mx, 32));
    if (!__all(mx <= mrow + 8.0f)){
      const float mn = fmaxf(mrow, mx);
      const float sc = __builtin_amdgcn_exp2f(mrow - mn);
      mrow = mn;
      lrow *= sc;
      #pragma unroll
      for (int nf = 0; nf < 8; nf++)
        #pragma unroll
        for (int r = 0; r < 16; r++) Oa[nf][r] *= sc;
    }
    float rs = 0.0f;
    #pragma unroll
    for (int r = 0; r < 16; r++){
      Sa[r] = __builtin_amdgcn_exp2f(Sa[r] - mrow); rs += Sa[r];
    }
    rs += __shfl_xor(rs, 32);
    lrow += rs;

    // ---- O += mfma(V, P): P B-frags via cvt_pk + shfl_xor(32) ----
    #pragma unroll
    for (int g = 0; g < 2; g++){
      unsigned int b0 = cvt_pk_bf16(Sa[g*8+0], Sa[g*8+1]);
      unsigned int b1 = cvt_pk_bf16(Sa[g*8+2], Sa[g*8+3]);
      unsigned int b2 = cvt_pk_bf16(Sa[g*8+4], Sa[g*8+5]);
      unsigned int b3 = cvt_pk_bf16(Sa[g*8+6], Sa[g*8+7]);
      unsigned int s0 = (unsigned int)__shfl_xor((int)b0, 32);
      unsigned int s1 = (unsigned int)__shfl_xor((int)b1, 32);
      unsigned int s2 = (unsigned int)__shfl_xor((int)b2, 32);
      unsigned int s3 = (unsigned int)__shfl_xor((int)b3, 32);
      union { uint4 u; short8 s; } pw;
      pw.u.x = hi2 ? s2 : b0;
      pw.u.y = hi2 ? s3 : b1;
      pw.u.z = hi2 ? b2 : s0;
      pw.u.w = hi2 ? b3 : s1;
      const short8 pb = pw.s;
      const int G = ch*4 + g*2 + hi2;   // absolute 8-kv chunk within 64
      #pragma unroll
      for (int nf = 0; nf < 8; nf++){
        const int c = nf*32 + l31;
        const int vr = c >> 2;
        const int slot = (((G << 2) | (c & 3)) ^ ((vr & 7) << 2));
        short8 va = *(const short8*)((const char*)Vb + vr*512 + slot*16);
        Oa[nf] = __builtin_amdgcn_mfma_f32_32x32x16_bf16(va, pb, Oa[nf], 0, 0, 0);
      }
    }

    __syncthreads();   // all waves done reading -> next STAGE may overwrite
  }
  #undef STAGE

  // ---- pair merge: ch=1 publishes (O, m, l); ch=0 combines + stores ----
  float* Ob = (qg < 2) ? (float*)&Kb[(qg & 1) * 16384] : (float*)&Vb[(qg & 1) * 16384];  // 16KB each? no:
  // qg in {0,1} -> halves of Kb (32KB/2 = 16KB is too small for 8KB*? ) -- need 32KB per qg:
  // O partial per qg = 256 cols x 32 rows x 4B = 32KB. Use Kb for qg0, Vb for qg1? But qg has 4 values.
  // Correct mapping (as v10): qg<2 -> Kb[qg]  (2x32KB slabs) ; here Kb is single 32KB.
  // Re-derive: publish only ch==1 partials, one per qg => 4 x 32KB = 128KB needed, we have 64KB.
  // Split the merge into two rounds over qg parity.
  Ob = nullptr;
  for (int round = 0; round < 2; round++){
    float* slab = (round == 0) ? (float*)&Kb[0] : (float*)&Vb[0];   // 32KB each round? need 2 qg per round
    // round 0: qg 0 uses Kb, qg 1 uses Vb; round 1: qg 2 uses Kb, qg 3 uses Vb
    const int myround = qg >> 1;
    float* myOb = ((qg & 1) == 0) ? (float*)&Kb[0] : (float*)&Vb[0];
    (void)slab;
    if (myround == round){
      if (ch == 1){
        #pragma unroll
        for (int nf = 0; nf < 8; nf++){
          #pragma unroll
          for (int r = 0; r < 16; r++){
            const int c = nf*32 + (r & 3) + 8*(r >> 2) + 4*hi2;
            myOb[c*32 + l31] = Oa[nf][r];
          }
        }
        if (hi2 == 0){ Mb[w][l31] = mrow; Lb[w][l31] = lrow; }
      }
    }
    __syncthreads();
    if (myround == round && ch == 0){
      const float m2 = Mb[w + 4][l31], l2 = Lb[w + 4][l31];
      const float mx = fmaxf(mrow, m2);
      const float f1 = __builtin_amdgcn_exp2f(mrow - mx);
      const float f2 = __builtin_amdgcn_exp2f(m2 - mx);
      const float inv = 1.0f / (f1*lrow + f2*l2);
      const float a1 = f1 * inv, a2 = f2 * inv;
      #pragma unroll
      for (int nf = 0; nf < 8; nf++){
        #pragma unroll
        for (int g = 0; g < 4; g++){
          float o0 = Oa[nf][g*4+0]*a1 + myOb[(nf*32 + g*8 + hi2*4 + 0)*32 + l31]*a2;
          float o1 = Oa[nf][g*4+1]*a1 + myOb[(nf*32 + g*8 + hi2*4 + 1)*32 + l31]*a2;
          float o2 = Oa[nf][g*4+2]*a1 + myOb[(nf*32 + g*8 + hi2*4 + 2)*32 + l31]*a2;
          float o3 = Oa[nf][g*4+3]*a1 + myOb[(nf*32 + g*8 + hi2*4 + 3)*32 + l31]*a2;
          uint2 ov;
          ov.x = cvt_pk_bf16(o0, o1);
          ov.y = cvt_pk_bf16(o2, o3);
          *(uint2*)(ogq + nf*32 + g*8 + hi2*4) = ov;
        }
      }
    }
    __syncthreads();
  }
}

extern "C" void kernel_launch(void* const* d_in, const int* in_sizes, int n_in,
                              void* d_out, int out_size, void* d_ws, size_t ws_size,
                              hipStream_t stream)
{
  (void)in_sizes; (void)n_in; (void)out_size;
  const void* x  = d_in[0];
  const void* WQ = d_in[1];
  const void* bQ = d_in[2];
  const void* WK = d_in[3];
  const void* bK = d_in[4];
  const void* WV = d_in[5];
  const void* bV = d_in[6];
  const void* Wo = d_in[7];
  const void* bo = d_in[8];

  const long long NE  = (long long)BB * SS * CC;
  const long long SC  = (long long)SS * CC;

  uint8_t* base = (uint8_t*)d_ws;
  float* biasF       = (float*)(base + 256);
  float* stats       = (float*)(base + 256 + 4096);
  ushort* WT         = (ushort*)(base + 256 + 4096 + 8192);
  ushort* h          = WT + 4 * 65536;

  const long long fixedB = 256 + 4096 + 8192 + 4LL*65536*2 + NE*2;
  int CB = 1;
  for (int c = 32; c >= 1; c >>= 1){
    if (fixedB + 4LL * c * SC * 2 <= (long long)ws_size){ CB = c; break; }
  }

  ushort* q  = h + NE;
  ushort* k  = q + (long long)CB * SC;
  ushort* vT = k + (long long)CB * SC;
  ushort* oC = vT + (long long)CB * SC;

  dim3 blk(256);
  const size_t shmem = 32768;

  pre_kernel<<<dim3(64 + GG*BB), blk, 0, stream>>>(x, WQ, WK, WV, Wo, bQ, bK, bV, bo, WT, biasF, stats);
  gn_norm<<<dim3(4, 16, BB), blk, 0, stream>>>(x, h, stats);

  for (int c0 = 0; c0 < BB; c0 += CB){
    const ushort* hC = h + (long long)c0 * SC;
    gemm128<0><<<dim3(CB*8, 2, 3), blk, shmem, stream>>>(
        hC, WT, q, CC, CC, CC, CC,
        0LL, 65536LL, (long long)CB * SC,
        biasF, nullptr, nullptr, vT, 0LL);
    attn_fused<<<dim3(CB, 8), dim3(512), 0, stream>>>(q, k, vT, oC);
    gemm128<3><<<dim3(CB*8, 2, 1), blk, shmem, stream>>>(
        oC, WT + 3*65536, nullptr, CC, CC, SS, CC,
        0LL, 0LL, 0LL,
        biasF, x, d_out, nullptr, (long long)c0 * SC);
  }
}

// Round 22
// 135.373 us; speedup vs baseline: 1.0161x; 1.0161x over previous
//
#include <hip/hip_runtime.h>
#include <stdint.h>

#define BB  32
#define CC  256
#define SS  1024
#define GG  32
#define GCH 8
#define EPS 1e-5f

typedef __attribute__((ext_vector_type(8))) short short8;
typedef __attribute__((ext_vector_type(4))) float f32x4;
typedef __attribute__((ext_vector_type(16))) float f32x16;
typedef unsigned short ushort;

__device__ __forceinline__ float bf2f(ushort u){
  union { unsigned int i; float f; } v; v.i = ((unsigned int)u) << 16; return v.f;
}
__device__ __forceinline__ ushort f2bf(float f){
  union { float f; unsigned int i; } v; v.f = f;
  unsigned int r = v.i + 0x7FFFu + ((v.i >> 16) & 1u);
  return (ushort)(r >> 16);
}
__device__ __forceinline__ unsigned int cvt_pk_bf16(float lo, float hi){
  unsigned int r;
  asm("v_cvt_pk_bf16_f32 %0, %1, %2" : "=v"(r) : "v"(lo), "v"(hi));
  return r;
}

// per-block dtype sniff: wave-uniform, same answer in every wave/block.
__device__ __forceinline__ int sniff_inline(const void* xp){
  const unsigned int* xw = (const unsigned int*)xp;
  const int lane = threadIdx.x & 63;
  int ok = 0;
  #pragma unroll
  for (int j = 0; j < 4; j++){
    unsigned int w = xw[lane*4 + j];
    ushort lo = (ushort)(w & 0xFFFFu);
    int e = (lo >> 7) & 0xFF;
    ok += (lo == 0 || (e >= 100 && e <= 130)) ? 1 : 0;
  }
  #pragma unroll
  for (int o = 32; o > 0; o >>= 1) ok += __shfl_down(ok, o);
  ok = __shfl(ok, 0);
  return ok > 192;
}

typedef __attribute__((address_space(3))) unsigned int lds_uint;
typedef const __attribute__((address_space(1))) unsigned int glob_uint;
__device__ __forceinline__ void ld_lds16(const void* g, void* l){
  __builtin_amdgcn_global_load_lds((glob_uint*)g, (lds_uint*)l, 16, 0, 0);
}

// ---------- fused pre-pass: blocks 0..63 convert weights/biases; 64..1087 GN stats ----------
// WT[z][n][k] = W[z][k][n] bf16; z==0 scaled by 1/16*log2(e) (exp2-domain softmax).
__global__ __launch_bounds__(256) void pre_kernel(
    const void* x,
    const void* w0, const void* w1, const void* w2, const void* w3,
    const void* b0, const void* b1, const void* b2, const void* b3,
    ushort* __restrict__ WT, float* __restrict__ biasF,
    float* __restrict__ stats)
{
  const int f = sniff_inline(x);
  const int tid = threadIdx.x;
  if (blockIdx.x < 64){
    const int id = blockIdx.x;
    const int z = id >> 4, yb = (id >> 2) & 3, xb = id & 3;
    const float scl = (z == 0) ? 0.0901684400557f : 1.0f;   // 0.0625 * log2(e)
    const void* wsel = z==0?w0:z==1?w1:z==2?w2:w3;
    ushort* dst = WT + (long long)z * 65536;
    __shared__ ushort t[64][65];
    const int tx = tid & 63, ty = tid >> 6;
    const int r0 = xb * 64, c0 = yb * 64;
    for (int j = 0; j < 64; j += 4){
      const int idx = (r0+ty+j)*256 + c0+tx;
      float v = f ? bf2f(((const ushort*)wsel)[idx]) : ((const float*)wsel)[idx];
      t[ty+j][tx] = f2bf(v * scl);
    }
    __syncthreads();
    for (int j = 0; j < 64; j += 4) dst[(c0+ty+j)*256 + r0+tx] = t[tx][ty+j];
    if (xb == 0 && yb == 0){
      const void* bsel = z==0?b0:z==1?b1:z==2?b2:b3;
      float bv = f ? bf2f(((const ushort*)bsel)[tid]) : ((const float*)bsel)[tid];
      biasF[z*256 + tid] = bv * scl;
    }
  } else {
    const int id = blockIdx.x - 64;
    const int g = id & 31, b = id >> 5;
    const long long base = ((long long)b * CC + g * GCH) * SS;
    float sum = 0.f, ss = 0.f;
    if (f){
      const ushort* xg = (const ushort*)x + base;
      #pragma unroll
      for (int j = 0; j < 4; j++){
        uint4 u = *(const uint4*)(xg + (j*256 + tid)*8);
        const ushort* e = (const ushort*)&u;
        #pragma unroll
        for (int i = 0; i < 8; i++){ float v = bf2f(e[i]); sum += v; ss += v*v; }
      }
    } else {
      const float* xg = (const float*)x + base;
      #pragma unroll
      for (int j = 0; j < 8; j++){
        float4 v4 = *(const float4*)(xg + (j*256 + tid)*4);
        sum += v4.x+v4.y+v4.z+v4.w;
        ss  += v4.x*v4.x+v4.y*v4.y+v4.z*v4.z+v4.w*v4.w;
      }
    }
    __shared__ float red[8];
    const int lane = tid & 63, w = tid >> 6;
    #pragma unroll
    for (int o = 32; o > 0; o >>= 1){
      sum += __shfl_down(sum, o);
      ss  += __shfl_down(ss, o);
    }
    if (lane == 0){ red[w] = sum; red[4+w] = ss; }
    __syncthreads();
    if (tid == 0){
      float s1 = red[0]+red[1]+red[2]+red[3];
      float s2 = red[4]+red[5]+red[6]+red[7];
      float mean = s1 / (float)(GCH*SS);
      float var  = s2 / (float)(GCH*SS) - mean*mean;
      const int idx = b*GG + g;
      stats[idx*2]   = mean;
      stats[idx*2+1] = rsqrtf(var + EPS);
    }
  }
}

// ---------- GN pass 2 ----------
__global__ __launch_bounds__(256) void gn_norm(const void* __restrict__ x,
                                               ushort* __restrict__ h,
                                               const float* __restrict__ stats)
{
  const int f = sniff_inline(x);
  const int c0 = blockIdx.x * 64, s0 = blockIdx.y * 64, b = blockIdx.z;
  const int tid = threadIdx.x;
  __shared__ ushort T[64][72];
  const int row = tid >> 2;
  const int qr  = tid & 3;
  const int g = (c0 + row) >> 3;
  const float mean = stats[(b*GG + g)*2];
  const float rstd = stats[(b*GG + g)*2 + 1];
  const long long xrow = ((long long)b * CC + c0 + row) * SS + s0;
  if (f){
    const ushort* xr = (const ushort*)x + xrow;
    #pragma unroll
    for (int j = 0; j < 2; j++){
      const int col = qr*16 + j*8;
      uint4 u = *(const uint4*)(xr + col);
      const ushort* e = (const ushort*)&u;
      #pragma unroll
      for (int i = 0; i < 8; i++) T[row][col+i] = f2bf((bf2f(e[i]) - mean) * rstd);
    }
  } else {
    const float* xr = (const float*)x + xrow;
    #pragma unroll
    for (int j = 0; j < 4; j++){
      const int col = qr*16 + j*4;
      float4 v4 = *(const float4*)(xr + col);
      T[row][col+0] = f2bf((v4.x - mean) * rstd);
      T[row][col+1] = f2bf((v4.y - mean) * rstd);
      T[row][col+2] = f2bf((v4.z - mean) * rstd);
      T[row][col+3] = f2bf((v4.w - mean) * rstd);
    }
  }
  __syncthreads();
  #pragma unroll
  for (int pass = 0; pass < 2; pass++){
    const int sr = pass*32 + (tid >> 3);
    const int cl = (tid & 7) * 8;
    ushort tmp[8];
    #pragma unroll
    for (int e = 0; e < 8; e++) tmp[e] = T[cl+e][sr];
    *(uint4*)(&h[((long long)b * SS + s0 + sr) * CC + c0 + cl]) = *(const uint4*)tmp;
  }
}

// ---------- generic 128x128 MFMA GEMM, m97-class staging ----------
template<int MODE>
__global__ __launch_bounds__(256) void gemm128(
    const ushort* __restrict__ A,
    const ushort* __restrict__ BT,
    ushort* __restrict__ Cmat,
    int lda, int ldb, int ldc, int K,
    long long sA, long long sB, long long sC,
    const float* __restrict__ biasF,
    const void* __restrict__ xres,
    void* __restrict__ outp,
    ushort* __restrict__ vTp,
    long long xoff)
{
  extern __shared__ __attribute__((aligned(16))) ushort smem[];
  ushort* As = smem;
  ushort* Bs = smem + 8192;
  const int tid  = threadIdx.x;
  const int lane = tid & 63;
  const int w    = tid >> 6;
  const int wr   = w >> 1, wc = w & 1;
  const int bz   = blockIdx.z;
  const int m0 = blockIdx.x * 128;
  const int n0 = blockIdx.y * 128;

  const int rr = lane & 15;
  const int hi = lane >> 4;
  const int crow = lane >> 3;
  const int pslot = lane & 7;

  f32x4 acc[4][4] = {};

  const ushort* Ab = A + (long long)bz * sA;
  const ushort* Bb = BT + (long long)bz * sB;

  for (int k0 = 0; k0 < K; k0 += 64){
    #pragma unroll
    for (int j = 0; j < 4; j++){
      const int ck = w*4 + j;
      const int r  = ck*8 + crow;
      const int s  = pslot ^ (r & 7);
      ld_lds16(Ab + (long long)(m0 + r) * lda + k0 + s*8, &As[ck * 512]);
    }
    #pragma unroll
    for (int j = 0; j < 4; j++){
      const int ck = w*4 + j;
      const int r  = ck*8 + crow;
      const int s  = pslot ^ (r & 7);
      ld_lds16(Bb + (long long)(n0 + r) * ldb + k0 + s*8, &Bs[ck * 512]);
    }
    asm volatile("s_waitcnt vmcnt(0)" ::: "memory");
    __builtin_amdgcn_sched_barrier(0);
    __syncthreads();

    #pragma unroll
    for (int kk = 0; kk < 2; kk++){
      short8 af[4], bfr[4];
      const int lbyte = kk*64 + hi*16;
      #pragma unroll
      for (int mf = 0; mf < 4; mf++){
        const int row = wr*64 + mf*16 + rr;
        af[mf] = *(const short8*)((const char*)As + row*128 + (lbyte ^ ((row & 7) << 4)));
      }
      #pragma unroll
      for (int nf = 0; nf < 4; nf++){
        const int row = wc*64 + nf*16 + rr;
        bfr[nf] = *(const short8*)((const char*)Bs + row*128 + (lbyte ^ ((row & 7) << 4)));
      }
      #pragma unroll
      for (int mf = 0; mf < 4; mf++)
        #pragma unroll
        for (int nf = 0; nf < 4; nf++)
          acc[mf][nf] = __builtin_amdgcn_mfma_f32_16x16x32_bf16(af[mf], bfr[nf], acc[mf][nf], 0, 0, 0);
    }
    __syncthreads();
  }

  const int rb = 4 * (lane >> 4);
  if (MODE == 0){
    if (bz < 2){
      ushort* Co = Cmat + (long long)bz * sC;
      #pragma unroll
      for (int mf = 0; mf < 4; mf++){
        #pragma unroll
        for (int nf = 0; nf < 4; nf++){
          const int col = n0 + wc*64 + nf*16 + rr;
          const float badd = biasF[bz*256 + col];
          #pragma unroll
          for (int r = 0; r < 4; r++){
            const int row = m0 + wr*64 + mf*16 + rb + r;
            Co[(long long)row * ldc + col] = f2bf(acc[mf][nf][r] + badd);
          }
        }
      }
    } else {
      // v: LDS-transpose then vectorized store to vT[b][c][s]
      #pragma unroll
      for (int mf = 0; mf < 4; mf++){
        #pragma unroll
        for (int nf = 0; nf < 4; nf++){
          const int colL = wc*64 + nf*16 + rr;
          const float badd = biasF[512 + n0 + colL];
          #pragma unroll
          for (int r = 0; r < 4; r++){
            const int rowL = wr*64 + mf*16 + rb + r;
            smem[colL * 128 + rowL] = f2bf(acc[mf][nf][r] + badd);
          }
        }
      }
      __syncthreads();
      const int bL = m0 >> 10;
      const int s0 = m0 & 1023;
      for (int i = tid; i < 2048; i += 256){
        const int colL = i >> 4;
        const int rowL = (i & 15) * 8;
        uint4 pv = *(const uint4*)(&smem[colL * 128 + rowL]);
        *(uint4*)(&vTp[((long long)bL * CC + n0 + colL) * SS + s0 + rowL]) = pv;
      }
    }
  } else {
    const int bL = m0 >> 10;
    const int s0 = m0 & 1023;
    #pragma unroll
    for (int mf = 0; mf < 4; mf++){
      #pragma unroll
      for (int nf = 0; nf < 4; nf++){
        const int colL = wc*64 + nf*16 + rr;
        const float badd = biasF[768 + n0 + colL];
        #pragma unroll
        for (int r = 0; r < 4; r++){
          const int rowL = wr*64 + mf*16 + rb + r;
          smem[colL * 128 + rowL] = f2bf(acc[mf][nf][r] + badd);
        }
      }
    }
    __syncthreads();
    const int f = sniff_inline(xres);
    for (int i = tid; i < 2048; i += 256){
      const int colL = i >> 4;
      const int rowL = (i & 15) * 8;
      const long long oi = xoff + ((long long)bL * CC + n0 + colL) * SS + s0 + rowL;
      const ushort* pu = &smem[colL * 128 + rowL];
      if (f){
        const ushort* xu = (const ushort*)xres + oi;
        ushort* ou = (ushort*)outp + oi;
        ushort tmp[8];
        #pragma unroll
        for (int e = 0; e < 8; e++) tmp[e] = f2bf(bf2f(xu[e]) + bf2f(pu[e]));
        *(uint4*)ou = *(const uint4*)tmp;
      } else {
        const float* xf = (const float*)xres + oi;
        float* of = (float*)outp + oi;
        float4 a0 = *(const float4*)xf;
        float4 a1 = *(const float4*)(xf + 4);
        float4 r0, r1;
        r0.x = a0.x + bf2f(pu[0]); r0.y = a0.y + bf2f(pu[1]);
        r0.z = a0.z + bf2f(pu[2]); r0.w = a0.w + bf2f(pu[3]);
        r1.x = a1.x + bf2f(pu[4]); r1.y = a1.y + bf2f(pu[5]);
        r1.z = a1.z + bf2f(pu[6]); r1.w = a1.w + bf2f(pu[7]);
        *(float4*)of = r0;
        *(float4*)(of + 4) = r1;
      }
    }
  }
}

// ---------- fused flash attention v10b: kv-split dedup, double-buffered K/V,
//            in-register exp2 softmax, cvt_pk P-build (best measured: 68 us) ----------
__global__ __launch_bounds__(512, 1) void attn_fused(
    const ushort* __restrict__ q, const ushort* __restrict__ k,
    const ushort* __restrict__ vT, ushort* __restrict__ oC)
{
  __shared__ ushort Kb[2][64 * 256];   // 64KB; reused as merge O buf (qg 0,1)
  __shared__ ushort Vb[2][256 * 64];   // 64KB; reused as merge O buf (qg 2,3)
  __shared__ float  Mb[8][32];
  __shared__ float  Lb[8][32];
  const int tid = threadIdx.x, lane = tid & 63, w = tid >> 6;
  const int l31 = lane & 31, hi2 = lane >> 5;
  const int qg = w & 3, ch = w >> 2;
  const int b = blockIdx.x, qt = blockIdx.y;

  const char* kgB = (const char*)(k + (long long)b * SS * CC);
  const char* vgB = (const char*)(vT + (long long)b * CC * SS);
  const int qrow = qt*128 + qg*32 + l31;
  const ushort* qgp = q + ((long long)b * SS + qrow) * CC + hi2*8;
  ushort* ogq = oC + ((long long)b * SS + qrow) * CC;

  short8 qf[16];
  #pragma unroll
  for (int kk = 0; kk < 16; kk++)
    qf[kk] = *(const short8*)(qgp + kk*16);

  f32x16 Oa[8] = {};
  float mrow = -1e30f, lrow = 0.0f;

  #define STAGE(buf, t0)                                                        \
  {                                                                             \
    _Pragma("unroll")                                                           \
    for (int j = 0; j < 4; j++){                                                \
      const int ck = j*8 + w;                                                   \
      const int tr = ck*2 + (lane >> 5);                                        \
      const int xb = ((lane & 31) * 16) ^ ((tr & 31) << 4);                     \
      ld_lds16(kgB + (long long)((t0) + tr) * 512 + xb, &Kb[buf][ck * 512]);    \
    }                                                                           \
    _Pragma("unroll")                                                           \
    for (int j = 0; j < 4; j++){                                                \
      const int ck = j*8 + w;                                                   \
      const int vr = ck*2 + (lane >> 5);                                        \
      const int u  = (lane & 31) ^ ((vr & 7) << 2);                             \
      const int vc = vr*4 + (u & 3);                                            \
      const int tb = (u >> 2) * 16;                                             \
      ld_lds16(vgB + (long long)vc * 2048 + (t0)*2 + tb, &Vb[buf][ck * 512]);   \
    }                                                                           \
  }

  STAGE(0, 0);
  asm volatile("s_waitcnt vmcnt(0)" ::: "memory");
  __builtin_amdgcn_sched_barrier(0);
  __syncthreads();

  const int coff = hi2 * 16;
  const int kswz = l31 << 4;
  const int krow = ch*32 + l31;   // this wave's K row within the tile

  for (int t = 0; t < 16; t++){
    const int cur = t & 1;
    if (t < 15) STAGE(cur ^ 1, (t+1)*64);

    // ---- S = mfma(K_half, Q): 16 MFMA; lane = q col l31, regs = kv rows ----
    f32x16 Sa = {};
    #pragma unroll
    for (int kk = 0; kk < 16; kk++){
      const int off = kk*32 + coff;
      short8 ka = *(const short8*)((const char*)&Kb[cur][0] + krow*512 + (off ^ kswz));
      Sa = __builtin_amdgcn_mfma_f32_32x32x16_bf16(ka, qf[kk], Sa, 0, 0, 0);
    }

    // ---- in-register online softmax over this wave's 32-kv half ----
    float mx = Sa[0];
    #pragma unroll
    for (int r = 1; r < 16; r++) mx = fmaxf(mx, Sa[r]);
    mx = fmaxf(mx, __shfl_xor(mx, 32));
    if (!__all(mx <= mrow + 8.0f)){
      const float mn = fmaxf(mrow, mx);
      const float sc = __builtin_amdgcn_exp2f(mrow - mn);
      mrow = mn;
      lrow *= sc;
      #pragma unroll
      for (int nf = 0; nf < 8; nf++)
        #pragma unroll
        for (int r = 0; r < 16; r++) Oa[nf][r] *= sc;
    }
    float rs = 0.0f;
    #pragma unroll
    for (int r = 0; r < 16; r++){
      Sa[r] = __builtin_amdgcn_exp2f(Sa[r] - mrow); rs += Sa[r];
    }
    rs += __shfl_xor(rs, 32);
    lrow += rs;

    // ---- O += mfma(V, P): P B-frags via cvt_pk + shfl_xor(32) ----
    #pragma unroll
    for (int g = 0; g < 2; g++){
      unsigned int b0 = cvt_pk_bf16(Sa[g*8+0], Sa[g*8+1]);
      unsigned int b1 = cvt_pk_bf16(Sa[g*8+2], Sa[g*8+3]);
      unsigned int b2 = cvt_pk_bf16(Sa[g*8+4], Sa[g*8+5]);
      unsigned int b3 = cvt_pk_bf16(Sa[g*8+6], Sa[g*8+7]);
      unsigned int s0 = (unsigned int)__shfl_xor((int)b0, 32);
      unsigned int s1 = (unsigned int)__shfl_xor((int)b1, 32);
      unsigned int s2 = (unsigned int)__shfl_xor((int)b2, 32);
      unsigned int s3 = (unsigned int)__shfl_xor((int)b3, 32);
      union { uint4 u; short8 s; } pw;
      pw.u.x = hi2 ? s2 : b0;
      pw.u.y = hi2 ? s3 : b1;
      pw.u.z = hi2 ? b2 : s0;
      pw.u.w = hi2 ? b3 : s1;
      const short8 pb = pw.s;
      const int G = ch*4 + g*2 + hi2;   // absolute 8-kv chunk within 64
      #pragma unroll
      for (int nf = 0; nf < 8; nf++){
        const int c = nf*32 + l31;
        const int vr = c >> 2;
        const int slot = (((G << 2) | (c & 3)) ^ ((vr & 7) << 2));
        short8 va = *(const short8*)((const char*)&Vb[cur][0] + vr*512 + slot*16);
        Oa[nf] = __builtin_amdgcn_mfma_f32_32x32x16_bf16(va, pb, Oa[nf], 0, 0, 0);
      }
    }

    asm volatile("s_waitcnt vmcnt(0)" ::: "memory");
    __builtin_amdgcn_sched_barrier(0);
    __syncthreads();
  }
  #undef STAGE

  // ---- pair merge: ch=1 publishes (O, m, l); ch=0 combines + stores ----
  float* Ob = (qg < 2) ? (float*)&Kb[qg][0] : (float*)&Vb[qg - 2][0];  // 32KB
  if (ch == 1){
    #pragma unroll
    for (int nf = 0; nf < 8; nf++){
      #pragma unroll
      for (int r = 0; r < 16; r++){
        const int c = nf*32 + (r & 3) + 8*(r >> 2) + 4*hi2;
        Ob[c*32 + l31] = Oa[nf][r];
      }
    }
    if (hi2 == 0){ Mb[w][l31] = mrow; Lb[w][l31] = lrow; }
  }
  __syncthreads();
  if (ch == 0){
    const float m2 = Mb[w + 4][l31], l2 = Lb[w + 4][l31];
    const float mx = fmaxf(mrow, m2);
    const float f1 = __builtin_amdgcn_exp2f(mrow - mx);
    const float f2 = __builtin_amdgcn_exp2f(m2 - mx);
    const float inv = 1.0f / (f1*lrow + f2*l2);
    const float a1 = f1 * inv, a2 = f2 * inv;
    #pragma unroll
    for (int nf = 0; nf < 8; nf++){
      #pragma unroll
      for (int g = 0; g < 4; g++){
        float o0 = Oa[nf][g*4+0]*a1 + Ob[(nf*32 + g*8 + hi2*4 + 0)*32 + l31]*a2;
        float o1 = Oa[nf][g*4+1]*a1 + Ob[(nf*32 + g*8 + hi2*4 + 1)*32 + l31]*a2;
        float o2 = Oa[nf][g*4+2]*a1 + Ob[(nf*32 + g*8 + hi2*4 + 2)*32 + l31]*a2;
        float o3 = Oa[nf][g*4+3]*a1 + Ob[(nf*32 + g*8 + hi2*4 + 3)*32 + l31]*a2;
        uint2 ov;
        ov.x = cvt_pk_bf16(o0, o1);
        ov.y = cvt_pk_bf16(o2, o3);
        *(uint2*)(ogq + nf*32 + g*8 + hi2*4) = ov;
      }
    }
  }
}

extern "C" void kernel_launch(void* const* d_in, const int* in_sizes, int n_in,
                              void* d_out, int out_size, void* d_ws, size_t ws_size,
                              hipStream_t stream)
{
  (void)in_sizes; (void)n_in; (void)out_size;
  const void* x  = d_in[0];
  const void* WQ = d_in[1];
  const void* bQ = d_in[2];
  const void* WK = d_in[3];
  const void* bK = d_in[4];
  const void* WV = d_in[5];
  const void* bV = d_in[6];
  const void* Wo = d_in[7];
  const void* bo = d_in[8];

  const long long NE  = (long long)BB * SS * CC;
  const long long SC  = (long long)SS * CC;

  uint8_t* base = (uint8_t*)d_ws;
  float* biasF       = (float*)(base + 256);
  float* stats       = (float*)(base + 256 + 4096);
  ushort* WT         = (ushort*)(base + 256 + 4096 + 8192);
  ushort* h          = WT + 4 * 65536;

  const long long fixedB = 256 + 4096 + 8192 + 4LL*65536*2 + NE*2;
  int CB = 1;
  for (int c = 32; c >= 1; c >>= 1){
    if (fixedB + 4LL * c * SC * 2 <= (long long)ws_size){ CB = c; break; }
  }

  ushort* q  = h + NE;
  ushort* k  = q + (long long)CB * SC;
  ushort* vT = k + (long long)CB * SC;
  ushort* oC = vT + (long long)CB * SC;

  dim3 blk(256);
  const size_t shmem = 32768;

  pre_kernel<<<dim3(64 + GG*BB), blk, 0, stream>>>(x, WQ, WK, WV, Wo, bQ, bK, bV, bo, WT, biasF, stats);
  gn_norm<<<dim3(4, 16, BB), blk, 0, stream>>>(x, h, stats);

  for (int c0 = 0; c0 < BB; c0 += CB){
    const ushort* hC = h + (long long)c0 * SC;
    gemm128<0><<<dim3(CB*8, 2, 3), blk, shmem, stream>>>(
        hC, WT, q, CC, CC, CC, CC,
        0LL, 65536LL, (long long)CB * SC,
        biasF, nullptr, nullptr, vT, 0LL);
    attn_fused<<<dim3(CB, 8), dim3(512), 0, stream>>>(q, k, vT, oC);
    gemm128<3><<<dim3(CB*8, 2, 1), blk, shmem, stream>>>(
        oC, WT + 3*65536, nullptr, CC, CC, SS, CC,
        0LL, 0LL, 0LL,
        biasF, x, d_out, nullptr, (long long)c0 * SC);
  }
}